// Round 2
// baseline (375.911 us; speedup 1.0000x reference)
//
#include <hip/hip_runtime.h>
#include <hip/hip_bf16.h>
#include <stdint.h>

#define ALPHA 1.0f

typedef __attribute__((ext_vector_type(8))) short bf16x8;
typedef __attribute__((ext_vector_type(4))) float f32x4;

__device__ __forceinline__ unsigned short f32_to_bf16_rne(float f) {
    union { float f; unsigned int u; } v; v.f = f;
    unsigned int u = v.u;
    unsigned int r = u + 0x7FFFu + ((u >> 16) & 1u);
    return (unsigned short)(r >> 16);
}

// packed f32x2 -> bf16x2 (RNE), single VALU instruction
__device__ __forceinline__ unsigned int cvt_pk_bf16(float lo, float hi) {
    unsigned int r;
    asm("v_cvt_pk_bf16_f32 %0, %1, %2" : "=v"(r) : "v"(lo), "v"(hi));
    return r;
}

__device__ __forceinline__ void async_copy16(const void* g, void* l) {
    __builtin_amdgcn_global_load_lds(
        (const __attribute__((address_space(1))) void*)g,
        (__attribute__((address_space(3))) void*)l, 16, 0, 0);
}

// ---------------------------------------------------------------------------
// Step 1a: t2[50][1024] = lora_up (50x4) @ (lora_down (4x100) @ down_aux (100x1024))
__global__ void lilora_t2_kernel(const float* __restrict__ lora_down,
                                 const float* __restrict__ lora_up,
                                 const float* __restrict__ down_aux,
                                 float* __restrict__ t2) {
    int i = threadIdx.x;  // 0..1023 column
    float t1[4] = {0.f, 0.f, 0.f, 0.f};
    for (int d = 0; d < 100; ++d) {
        float da = down_aux[d * 1024 + i];
#pragma unroll
        for (int r = 0; r < 4; ++r) t1[r] += lora_down[r * 100 + d] * da;
    }
    for (int u = 0; u < 50; ++u) {
        float acc = 0.f;
#pragma unroll
        for (int r = 0; r < 4; ++r) acc += lora_up[u * 4 + r] * t1[r];
        t2[u * 1024 + i] = acc;
    }
}

// ---------------------------------------------------------------------------
// Step 1b: W_eff[o][i] = W[o][i] + ALPHA * sum_u up_aux[o][u] * t2[u][i]  (bf16 out)
__global__ __launch_bounds__(256)
void weff_bf16_kernel(const float* __restrict__ W, const float* __restrict__ up_aux,
                      const float* __restrict__ t2, unsigned short* __restrict__ weff) {
    int o = blockIdx.x;
    int i0 = threadIdx.x * 4;
    float4 acc = *(const float4*)(W + (long)o * 1024 + i0);
    for (int u = 0; u < 50; ++u) {
        float s = up_aux[o * 50 + u] * ALPHA;
        float4 t = *(const float4*)(t2 + u * 1024 + i0);
        acc.x += s * t.x; acc.y += s * t.y; acc.z += s * t.z; acc.w += s * t.w;
    }
    ushort4 r;
    r.x = f32_to_bf16_rne(acc.x);
    r.y = f32_to_bf16_rne(acc.y);
    r.z = f32_to_bf16_rne(acc.z);
    r.w = f32_to_bf16_rne(acc.w);
    *(ushort4*)(weff + (long)o * 1024 + i0) = r;
}

// f32 variant for the fallback path
__global__ __launch_bounds__(256)
void weff_f32_kernel(const float* __restrict__ W, const float* __restrict__ up_aux,
                     const float* __restrict__ t2, float* __restrict__ weff) {
    int o = blockIdx.x;
    int i0 = threadIdx.x * 4;
    float4 acc = *(const float4*)(W + (long)o * 1024 + i0);
    for (int u = 0; u < 50; ++u) {
        float s = up_aux[o * 50 + u] * ALPHA;
        float4 t = *(const float4*)(t2 + u * 1024 + i0);
        acc.x += s * t.x; acc.y += s * t.y; acc.z += s * t.z; acc.w += s * t.w;
    }
    *(float4*)(weff + (long)o * 1024 + i0) = acc;
}

// ---------------------------------------------------------------------------
// Fused GEMM: C[M][N] = cvt_bf16(A_f32[M][K]) * Bt_bf16[N][K]^T + bias
// 128x128 tile, BK=64, 4 waves (2x2), each wave 64x64 = 4x4 frags of 16x16x32.
// LDS tiles are [row][64] bf16 = 128B rows, XOR-swizzled in 16B chunks:
//   chunk' = chunk ^ (row & 7)   (bijective involution within each 8-row stripe)
// A is reg-staged (f32->bf16 cvt) so the ds_write applies the swizzle directly.
// B uses global_load_lds (linear LDS dest) with a pre-swizzled GLOBAL source.
#define BM 128
#define BN 128
#define BK 64

__global__ __launch_bounds__(256, 2)
void gemm_fused_kernel(const float* __restrict__ A,
                       const unsigned short* __restrict__ Bt,
                       const float* __restrict__ bias,
                       float* __restrict__ C, int M, int N, int K) {
    __shared__ __align__(16) unsigned short As[BM * BK];  // 16 KB
    __shared__ __align__(16) unsigned short Bs[BN * BK];  // 16 KB

    int nTilesN = N / BN;
    int nwg = gridDim.x;
    int bid = blockIdx.x;
    // XCD-aware swizzle (bijective when nwg % 8 == 0; here grid = 4096)
    int swz = bid;
    if ((nwg & 7) == 0) {
        int cpx = nwg >> 3;
        swz = (bid & 7) * cpx + (bid >> 3);
    }
    int tm = swz / nTilesN;   // tn fastest -> the 8 blocks sharing an A panel
    int tn = swz % nTilesN;   // run back-to-back on the same XCD (A L2-hot)

    int tid = threadIdx.x;
    int lane = tid & 63;
    int wave = tid >> 6;   // 0..3
    int wr = wave >> 1;    // 0..1
    int wc = wave & 1;     // 0..1

    const long rowA0 = (long)tm * BM;
    const long colB0 = (long)tn * BN;

    // ---- A staging geometry: thread t -> row ar, half ah (32 f32 each) ----
    int ar = tid >> 1;          // 0..127
    int ah = tid & 1;           // 0..1
    const float* aBase = A + (rowA0 + ar) * (long)K + ah * 32;

    // ---- B staging geometry (pre-swizzled global source) ----
    // copy q: lds chunk pc = q*256 + tid ; row = pc>>3 ; c' = pc&7 ;
    // logical chunk c = c' ^ (row&7) ; global addr = row*K + k0 + c*8 elems
    int brow[4], bchk[4];
#pragma unroll
    for (int q = 0; q < 4; ++q) {
        int pc = q * 256 + tid;
        brow[q] = pc >> 3;
        bchk[q] = (pc & 7) ^ (brow[q] & 7);
    }

    f32x4 acc[4][4];
#pragma unroll
    for (int m = 0; m < 4; ++m)
#pragma unroll
        for (int n = 0; n < 4; ++n) acc[m][n] = (f32x4)(0.0f);

    int fr = lane & 15;          // fragment row
    int h4 = lane >> 4;          // k-chunk within 32-k slice
    int fr7 = fr & 7;            // row&7 for swizzle (m*16, wr*64 are 0 mod 8)

    // prologue: load A regs for k0 = 0
    float4 vA[8];
#pragma unroll
    for (int j = 0; j < 8; ++j) vA[j] = ((const float4*)aBase)[j];

    const int nIter = K / BK;   // 16
    for (int it = 0; it < nIter; ++it) {
        int k0 = it * BK;
        __syncthreads();   // previous tile's LDS reads done (+ drains vA loads)

        // stage B tile (async, direct to LDS, source pre-swizzled)
#pragma unroll
        for (int q = 0; q < 4; ++q) {
            const unsigned short* gp =
                Bt + (colB0 + brow[q]) * (long)K + k0 + bchk[q] * 8;
            unsigned short* lp = Bs + q * 2048 + wave * 512;  // wave-uniform base
            async_copy16(gp, lp);
        }

        // stage A tile: convert the pre-loaded f32 regs -> bf16, swizzled ds_write
        unsigned int pk[16];
#pragma unroll
        for (int j = 0; j < 8; ++j) {
            pk[2 * j]     = cvt_pk_bf16(vA[j].x, vA[j].y);
            pk[2 * j + 1] = cvt_pk_bf16(vA[j].z, vA[j].w);
        }
#pragma unroll
        for (int cc = 0; cc < 4; ++cc) {
            int c = (ah * 4 + cc) ^ (ar & 7);
            uint4 w = make_uint4(pk[4 * cc], pk[4 * cc + 1], pk[4 * cc + 2], pk[4 * cc + 3]);
            *(uint4*)(&As[ar * 64 + c * 8]) = w;
        }

        __syncthreads();   // drain B async copies + A ds_writes

        // issue next iteration's A loads here so they overlap the MFMA cluster
        if (it + 1 < nIter) {
            const float* ap = aBase + k0 + BK;
#pragma unroll
            for (int j = 0; j < 8; ++j) vA[j] = ((const float4*)ap)[j];
        }

        // MFMA: two 16x16x32 k-slices over BK=64
#pragma unroll
        for (int kk = 0; kk < 2; ++kk) {
            bf16x8 a[4], b[4];
            int cidx = ((kk << 2) + h4);
#pragma unroll
            for (int m = 0; m < 4; ++m) {
                int row = wr * 64 + m * 16 + fr;
                a[m] = *(const bf16x8*)(&As[row * 64 + (cidx ^ fr7) * 8]);
            }
#pragma unroll
            for (int n = 0; n < 4; ++n) {
                int row = wc * 64 + n * 16 + fr;
                b[n] = *(const bf16x8*)(&Bs[row * 64 + (cidx ^ fr7) * 8]);
            }
#pragma unroll
            for (int m = 0; m < 4; ++m)
#pragma unroll
                for (int n = 0; n < 4; ++n)
                    acc[m][n] = __builtin_amdgcn_mfma_f32_16x16x32_bf16(a[m], b[n], acc[m][n], 0, 0, 0);
        }
    }

    // epilogue: C[row][col] = acc + bias[col]
    int ccol = lane & 15;
    int crow = (lane >> 4) * 4;
#pragma unroll
    for (int m = 0; m < 4; ++m) {
        long grow = rowA0 + wr * 64 + m * 16 + crow;
#pragma unroll
        for (int n = 0; n < 4; ++n) {
            long gcol = colB0 + wc * 64 + n * 16 + ccol;
            float bb = bias[gcol];
#pragma unroll
            for (int r = 0; r < 4; ++r) {
                C[(grow + r) * N + gcol] = acc[m][n][r] + bb;
            }
        }
    }
}

// ---------------------------------------------------------------------------
// Fallback: plain f32 tiled GEMM (used only if ws too small for bf16 path)
__global__ __launch_bounds__(256)
void gemm_f32_fallback(const float* __restrict__ A, const float* __restrict__ Bt,
                       const float* __restrict__ bias, float* __restrict__ C,
                       int M, int N, int K) {
    __shared__ float As[64][17];
    __shared__ float Bs[64][17];
    int tilesN = N / 64;
    int tm = blockIdx.x / tilesN;
    int tn = blockIdx.x % tilesN;
    int tid = threadIdx.x;
    int tr = tid / 16, tc = tid % 16;
    float acc[4][4] = {};
    for (int k0 = 0; k0 < K; k0 += 16) {
        for (int t = tid; t < 64 * 16; t += 256) {
            int r = t / 16, c = t % 16;
            As[r][c] = A[((long)tm * 64 + r) * K + k0 + c];
            Bs[r][c] = Bt[((long)tn * 64 + r) * K + k0 + c];
        }
        __syncthreads();
#pragma unroll
        for (int kk = 0; kk < 16; ++kk) {
            float av[4], bv[4];
#pragma unroll
            for (int i = 0; i < 4; ++i) av[i] = As[tr * 4 + i][kk];
#pragma unroll
            for (int j = 0; j < 4; ++j) bv[j] = Bs[tc * 4 + j][kk];
#pragma unroll
            for (int i = 0; i < 4; ++i)
#pragma unroll
                for (int j = 0; j < 4; ++j) acc[i][j] += av[i] * bv[j];
        }
        __syncthreads();
    }
#pragma unroll
    for (int i = 0; i < 4; ++i) {
        long row = (long)tm * 64 + tr * 4 + i;
#pragma unroll
        for (int j = 0; j < 4; ++j) {
            long col = (long)tn * 64 + tc * 4 + j;
            C[row * N + col] = acc[i][j] + bias[col];
        }
    }
}

// ---------------------------------------------------------------------------
extern "C" void kernel_launch(void* const* d_in, const int* in_sizes, int n_in,
                              void* d_out, int out_size, void* d_ws, size_t ws_size,
                              hipStream_t stream) {
    const float* hs        = (const float*)d_in[0];
    const float* W         = (const float*)d_in[1];
    const float* b         = (const float*)d_in[2];
    const float* lora_down = (const float*)d_in[3];
    const float* lora_up   = (const float*)d_in[4];
    const float* down_aux  = (const float*)d_in[5];
    const float* up_aux    = (const float*)d_in[6];
    float* out = (float*)d_out;

    const int K = 1024;   // IN
    const int N = 1024;   // OUT
    const int M = in_sizes[0] / K;  // B*S = 65536

    char* ws = (char*)d_ws;
    // layout: t2 f32 [50*1024] @0 ; weff @256KB (bf16: 2MB, f32 fallback: 4MB)
    float* t2 = (float*)ws;
    const size_t OFF_WEFF = 256 * 1024;
    const size_t NEED_FAST = OFF_WEFF + 2 * 1024 * 1024;

    // Step 1a: t2
    lilora_t2_kernel<<<1, 1024, 0, stream>>>(lora_down, lora_up, down_aux, t2);

    if (ws_size >= NEED_FAST) {
        unsigned short* weff = (unsigned short*)(ws + OFF_WEFF);
        // Step 1b: W_eff bf16
        weff_bf16_kernel<<<N, 256, 0, stream>>>(W, up_aux, t2, weff);
        // Step 2: fused cvt+GEMM
        int grid = (M / BM) * (N / BN);
        gemm_fused_kernel<<<grid, 256, 0, stream>>>(hs, weff, b, out, M, N, K);
    } else {
        // fallback: f32 path (needs ~4.3 MB ws)
        float* weff = (float*)(ws + OFF_WEFF);
        weff_f32_kernel<<<N, 256, 0, stream>>>(W, up_aux, t2, weff);
        int grid = (M / 64) * (N / 64);
        gemm_f32_fallback<<<grid, 256, 0, stream>>>(hs, weff, b, out, M, N, K);
    }
}

// Round 3
// 263.125 us; speedup vs baseline: 1.4286x; 1.4286x over previous
//
#include <hip/hip_runtime.h>
#include <hip/hip_bf16.h>
#include <stdint.h>

#define ALPHA 1.0f

typedef __attribute__((ext_vector_type(8))) short bf16x8;
typedef __attribute__((ext_vector_type(4))) float f32x4;

__device__ __forceinline__ unsigned short f32_to_bf16_rne(float f) {
    union { float f; unsigned int u; } v; v.f = f;
    unsigned int u = v.u;
    unsigned int r = u + 0x7FFFu + ((u >> 16) & 1u);
    return (unsigned short)(r >> 16);
}

// packed f32x2 -> bf16x2 (RNE), single VALU instruction; word = [lo, hi]
__device__ __forceinline__ unsigned int cvt_pk_bf16(float lo, float hi) {
    unsigned int r;
    asm("v_cvt_pk_bf16_f32 %0, %1, %2" : "=v"(r) : "v"(lo), "v"(hi));
    return r;
}

__device__ __forceinline__ void async_copy16(const void* g, void* l) {
    __builtin_amdgcn_global_load_lds(
        (const __attribute__((address_space(1))) void*)g,
        (__attribute__((address_space(3))) void*)l, 16, 0, 0);
}

// ---------------------------------------------------------------------------
// Step 1a: t2[50][1024] = lora_up (50x4) @ (lora_down (4x100) @ down_aux (100x1024))
__global__ void lilora_t2_kernel(const float* __restrict__ lora_down,
                                 const float* __restrict__ lora_up,
                                 const float* __restrict__ down_aux,
                                 float* __restrict__ t2) {
    int i = threadIdx.x;  // 0..1023 column
    float t1[4] = {0.f, 0.f, 0.f, 0.f};
    for (int d = 0; d < 100; ++d) {
        float da = down_aux[d * 1024 + i];
#pragma unroll
        for (int r = 0; r < 4; ++r) t1[r] += lora_down[r * 100 + d] * da;
    }
    for (int u = 0; u < 50; ++u) {
        float acc = 0.f;
#pragma unroll
        for (int r = 0; r < 4; ++r) acc += lora_up[u * 4 + r] * t1[r];
        t2[u * 1024 + i] = acc;
    }
}

// ---------------------------------------------------------------------------
// Step 1b: W_eff[o][i] = W[o][i] + ALPHA * sum_u up_aux[o][u] * t2[u][i]  (bf16 out)
__global__ __launch_bounds__(256)
void weff_bf16_kernel(const float* __restrict__ W, const float* __restrict__ up_aux,
                      const float* __restrict__ t2, unsigned short* __restrict__ weff) {
    int o = blockIdx.x;
    int i0 = threadIdx.x * 4;
    float4 acc = *(const float4*)(W + (long)o * 1024 + i0);
    for (int u = 0; u < 50; ++u) {
        float s = up_aux[o * 50 + u] * ALPHA;
        float4 t = *(const float4*)(t2 + u * 1024 + i0);
        acc.x += s * t.x; acc.y += s * t.y; acc.z += s * t.z; acc.w += s * t.w;
    }
    ushort4 r;
    r.x = f32_to_bf16_rne(acc.x);
    r.y = f32_to_bf16_rne(acc.y);
    r.z = f32_to_bf16_rne(acc.z);
    r.w = f32_to_bf16_rne(acc.w);
    *(ushort4*)(weff + (long)o * 1024 + i0) = r;
}

// f32 variant for the fallback path
__global__ __launch_bounds__(256)
void weff_f32_kernel(const float* __restrict__ W, const float* __restrict__ up_aux,
                     const float* __restrict__ t2, float* __restrict__ weff) {
    int o = blockIdx.x;
    int i0 = threadIdx.x * 4;
    float4 acc = *(const float4*)(W + (long)o * 1024 + i0);
    for (int u = 0; u < 50; ++u) {
        float s = up_aux[o * 50 + u] * ALPHA;
        float4 t = *(const float4*)(t2 + u * 1024 + i0);
        acc.x += s * t.x; acc.y += s * t.y; acc.z += s * t.z; acc.w += s * t.w;
    }
    *(float4*)(weff + (long)o * 1024 + i0) = acc;
}

// ---------------------------------------------------------------------------
// Fused GEMM: C[M][N] = cvt_bf16(A_f32[M][K]) * Bt_bf16[N][K]^T + bias
// 128x128 tile, BK=64, 4 waves (2x2), wave = 64x64 out = 4x4 frags 16x16x32.
//
// A staged into LDS as RAW F32 via global_load_lds (no register round-trip);
// f32->bf16 conversion happens at fragment-load time (v_cvt_pk_bf16_f32,
// overlapped with MFMA by the scheduler). B staged as bf16 via global_load_lds.
// Both tiles XOR-swizzled in 16B chunks via PRE-SWIZZLED GLOBAL SOURCE
// (LDS dest stays linear, rule #21): chunk' = chunk ^ (row&7).
//  - A rows: 64 f32 = 256B = 16 chunks; B rows: 64 bf16 = 128B = 8 chunks.
//  - fragment reads: within each 16-lane quarter, rows 0..15 spread across
//    all 8 chunk slots of a 128B wrap -> 2 lanes/bank = conflict-free.
#define BM 128
#define BN 128
#define BK 64

__global__ __launch_bounds__(256, 3)
void gemm_fused_kernel(const float* __restrict__ A,
                       const unsigned short* __restrict__ Bt,
                       const float* __restrict__ bias,
                       float* __restrict__ C, int M, int N, int K) {
    __shared__ __align__(16) float Asf[BM * BK];           // 32 KB (f32!)
    __shared__ __align__(16) unsigned short Bs[BN * BK];   // 16 KB

    int nTilesN = N / BN;
    int nwg = gridDim.x;
    int bid = blockIdx.x;
    // XCD-aware swizzle (bijective when nwg % 8 == 0; here grid = 4096)
    int swz = bid;
    if ((nwg & 7) == 0) {
        int cpx = nwg >> 3;
        swz = (bid & 7) * cpx + (bid >> 3);
    }
    int tm = swz / nTilesN;   // tn fastest -> 8 blocks sharing an A panel
    int tn = swz % nTilesN;   // run back-to-back on the same XCD (A L2-hot)

    int tid = threadIdx.x;
    int lane = tid & 63;
    int wave = tid >> 6;   // 0..3
    int wr = wave >> 1;    // 0..1
    int wc = wave & 1;     // 0..1

    const long rowA0 = (long)tm * BM;
    const long colB0 = (long)tn * BN;

    // ---- A staging geometry (8 copies of 16B/thread), pre-swizzled source --
    // copy q: chunk pc = q*256+tid ; row = pc>>4 ; c' = pc&15 ;
    // logical chunk c = c' ^ (row&7) ; global f32 offset = row*K + k0 + c*4
    int arow[8], achk[8];
#pragma unroll
    for (int q = 0; q < 8; ++q) {
        int pc = q * 256 + tid;
        arow[q] = pc >> 4;
        achk[q] = (pc & 15) ^ (arow[q] & 7);
    }

    // ---- B staging geometry (4 copies of 16B/thread), pre-swizzled source --
    int brow[4], bchk[4];
#pragma unroll
    for (int q = 0; q < 4; ++q) {
        int pc = q * 256 + tid;
        brow[q] = pc >> 3;
        bchk[q] = (pc & 7) ^ (brow[q] & 7);
    }

    f32x4 acc[4][4];
#pragma unroll
    for (int m = 0; m < 4; ++m)
#pragma unroll
        for (int n = 0; n < 4; ++n) acc[m][n] = (f32x4)(0.0f);

    int fr = lane & 15;          // fragment row
    int h4 = lane >> 4;          // k-group within 32-k slice
    int s7 = fr & 7;             // swizzle key (wr*64, m*16 are 0 mod 8)

    const int nIter = K / BK;   // 16
    for (int it = 0; it < nIter; ++it) {
        int k0 = it * BK;
        __syncthreads();   // previous tile's LDS reads done

        // stage A tile (f32, async direct to LDS, source pre-swizzled)
#pragma unroll
        for (int q = 0; q < 8; ++q) {
            const float* gp = A + (rowA0 + arow[q]) * (long)K + k0 + achk[q] * 4;
            float* lp = Asf + q * 1024 + wave * 256;   // wave-uniform base
            async_copy16(gp, lp);
        }
        // stage B tile (bf16, async, source pre-swizzled)
#pragma unroll
        for (int q = 0; q < 4; ++q) {
            const unsigned short* gp =
                Bt + (colB0 + brow[q]) * (long)K + k0 + bchk[q] * 8;
            unsigned short* lp = Bs + q * 2048 + wave * 512;
            async_copy16(gp, lp);
        }

        __syncthreads();   // drain async copies (compiler emits vmcnt(0))

        // MFMA: two 16x16x32 k-slices over BK=64
#pragma unroll
        for (int kk = 0; kk < 2; ++kk) {
            bf16x8 a[4], b[4];
            int cbA = kk * 8 + h4 * 2;   // A chunk base (16B units of 4 f32)
            int cB  = (kk * 4 + h4) ^ s7; // B chunk (16B units of 8 bf16)
#pragma unroll
            for (int m = 0; m < 4; ++m) {
                int row = wr * 64 + m * 16 + fr;
                const float* rp = Asf + row * 64;
                float4 lo = *(const float4*)(rp + ((cbA + 0) ^ s7) * 4);
                float4 hi = *(const float4*)(rp + ((cbA + 1) ^ s7) * 4);
                union { unsigned int u[4]; bf16x8 v; } pk;
                pk.u[0] = cvt_pk_bf16(lo.x, lo.y);
                pk.u[1] = cvt_pk_bf16(lo.z, lo.w);
                pk.u[2] = cvt_pk_bf16(hi.x, hi.y);
                pk.u[3] = cvt_pk_bf16(hi.z, hi.w);
                a[m] = pk.v;
            }
#pragma unroll
            for (int n = 0; n < 4; ++n) {
                int row = wc * 64 + n * 16 + fr;
                b[n] = *(const bf16x8*)(&Bs[row * 64 + cB * 8]);
            }
#pragma unroll
            for (int m = 0; m < 4; ++m)
#pragma unroll
                for (int n = 0; n < 4; ++n)
                    acc[m][n] = __builtin_amdgcn_mfma_f32_16x16x32_bf16(a[m], b[n], acc[m][n], 0, 0, 0);
        }
    }

    // epilogue: C[row][col] = acc + bias[col]
    int ccol = lane & 15;
    int crow = (lane >> 4) * 4;
#pragma unroll
    for (int m = 0; m < 4; ++m) {
        long grow = rowA0 + wr * 64 + m * 16 + crow;
#pragma unroll
        for (int n = 0; n < 4; ++n) {
            long gcol = colB0 + wc * 64 + n * 16 + ccol;
            float bb = bias[gcol];
#pragma unroll
            for (int r = 0; r < 4; ++r) {
                C[(grow + r) * N + gcol] = acc[m][n][r] + bb;
            }
        }
    }
}

// ---------------------------------------------------------------------------
// Fallback: plain f32 tiled GEMM (used only if ws too small for bf16 path)
__global__ __launch_bounds__(256)
void gemm_f32_fallback(const float* __restrict__ A, const float* __restrict__ Bt,
                       const float* __restrict__ bias, float* __restrict__ C,
                       int M, int N, int K) {
    __shared__ float As[64][17];
    __shared__ float Bs[64][17];
    int tilesN = N / 64;
    int tm = blockIdx.x / tilesN;
    int tn = blockIdx.x % tilesN;
    int tid = threadIdx.x;
    int tr = tid / 16, tc = tid % 16;
    float acc[4][4] = {};
    for (int k0 = 0; k0 < K; k0 += 16) {
        for (int t = tid; t < 64 * 16; t += 256) {
            int r = t / 16, c = t % 16;
            As[r][c] = A[((long)tm * 64 + r) * K + k0 + c];
            Bs[r][c] = Bt[((long)tn * 64 + r) * K + k0 + c];
        }
        __syncthreads();
#pragma unroll
        for (int kk = 0; kk < 16; ++kk) {
            float av[4], bv[4];
#pragma unroll
            for (int i = 0; i < 4; ++i) av[i] = As[tr * 4 + i][kk];
#pragma unroll
            for (int j = 0; j < 4; ++j) bv[j] = Bs[tc * 4 + j][kk];
#pragma unroll
            for (int i = 0; i < 4; ++i)
#pragma unroll
                for (int j = 0; j < 4; ++j) acc[i][j] += av[i] * bv[j];
        }
        __syncthreads();
    }
#pragma unroll
    for (int i = 0; i < 4; ++i) {
        long row = (long)tm * 64 + tr * 4 + i;
#pragma unroll
        for (int j = 0; j < 4; ++j) {
            long col = (long)tn * 64 + tc * 4 + j;
            C[row * N + col] = acc[i][j] + bias[col];
        }
    }
}

// ---------------------------------------------------------------------------
extern "C" void kernel_launch(void* const* d_in, const int* in_sizes, int n_in,
                              void* d_out, int out_size, void* d_ws, size_t ws_size,
                              hipStream_t stream) {
    const float* hs        = (const float*)d_in[0];
    const float* W         = (const float*)d_in[1];
    const float* b         = (const float*)d_in[2];
    const float* lora_down = (const float*)d_in[3];
    const float* lora_up   = (const float*)d_in[4];
    const float* down_aux  = (const float*)d_in[5];
    const float* up_aux    = (const float*)d_in[6];
    float* out = (float*)d_out;

    const int K = 1024;   // IN
    const int N = 1024;   // OUT
    const int M = in_sizes[0] / K;  // B*S = 65536

    char* ws = (char*)d_ws;
    // layout: t2 f32 [50*1024] @0 ; weff @256KB (bf16: 2MB, f32 fallback: 4MB)
    float* t2 = (float*)ws;
    const size_t OFF_WEFF = 256 * 1024;
    const size_t NEED_FAST = OFF_WEFF + 2 * 1024 * 1024;

    // Step 1a: t2
    lilora_t2_kernel<<<1, 1024, 0, stream>>>(lora_down, lora_up, down_aux, t2);

    if (ws_size >= NEED_FAST) {
        unsigned short* weff = (unsigned short*)(ws + OFF_WEFF);
        // Step 1b: W_eff bf16
        weff_bf16_kernel<<<N, 256, 0, stream>>>(W, up_aux, t2, weff);
        // Step 2: fused cvt+GEMM
        int grid = (M / BM) * (N / BN);
        gemm_fused_kernel<<<grid, 256, 0, stream>>>(hs, weff, b, out, M, N, K);
    } else {
        // fallback: f32 path (needs ~4.3 MB ws)
        float* weff = (float*)(ws + OFF_WEFF);
        weff_f32_kernel<<<N, 256, 0, stream>>>(W, up_aux, t2, weff);
        int grid = (M / 64) * (N / 64);
        gemm_f32_fallback<<<grid, 64 * 4, 0, stream>>>(hs, weff, b, out, M, N, K);
    }
}